// Round 1
// 673.488 us; speedup vs baseline: 1.1593x; 1.1593x over previous
//
#include <hip/hip_runtime.h>

// WindowAttention (Swin-style), MI355X gfx950.
// B=16, L=3136, N=16 tok, C=96, H=8 heads, D=12.
// ALL inputs/outputs are FP32 (per reference); compute uses bf16 MFMA 16x16x32.
// One wave processes whole windows end-to-end.
//
// R1 change vs baseline (latency-bound: MfmaUtil 6.8%, VALUBusy 25%, HBM 13%):
//  - phase 2 head-BATCHED: 8 score MFMAs -> 8 independent softmax chains ->
//    8 A-writes -> ONE lds_fence -> 8 PV MFMAs. (was: 8x serial chains, each
//    with its own lgkmcnt(0) fence). 8 A slots instead of 2.
//  - V buffer shrunk to its true 12 d-rows (d>=12 reads -> zero page) to fit
//    the extra A slots: LDS 162880 <= 163840.
//  - per-window __syncthreads() removed (waves own disjoint LDS; WQ read-only).
//  - next window's x + mask prefetched one iteration ahead (hides HBM latency).

typedef __attribute__((ext_vector_type(4))) float f32x4;
typedef __attribute__((ext_vector_type(8))) short s16x8;
typedef __attribute__((ext_vector_type(4))) short s16x4;

#define DEV __device__ __forceinline__

DEV short f2bf(float f) {   // RNE round to bf16
    union { float f; unsigned int i; } v; v.f = f;
    unsigned int u = v.i;
    u += 0x7FFFu + ((u >> 16) & 1u);
    return (short)(u >> 16);
}
// Wave-local LDS fence: forbid compiler reordering across it AND drain lgkm.
DEV void lds_fence() { asm volatile("s_waitcnt lgkmcnt(0)" ::: "memory"); }

#define LOG2E  1.4426950408889634f
#define QSCALE (0.2886751345948129f * 1.4426950408889634f)  // D^-0.5 * log2(e)
#define LBASE  3136
#define WIN_PER_WAVE 49   // 50176 windows / (256 blocks * 4 waves)

// ---- LDS layout (bytes) ----
#define WQ_OFF   0
#define WQ_SZ    (96*288*2)        // 55296: Wqkv(bf16) in fragment layout, 54 chunks x 1024B
#define ZP_OFF   WQ_SZ             // 64B zero page (for K-padding reads)
#define WAVE_BASE (WQ_SZ + 64)
// per-wave buffers:
#define PW_Q     0                 // q_s [16 tok][8h*16d pad] bf16, row 272B = 4352B
#define PW_K     4352
#define PW_V     8704              // v_s [8h][12d][24 tok-pad] bf16, 576B/head = 4608B
#define PW_A     13312             // a_s 8 slots x [16 i][40 j-pad] bf16 = 8x1280B
#define PW_O     23552             // o_s [16 tok][104 f-pad] bf16 = 3328B (row 208B)
#define PW_STRIDE 26880
#define SMEM_TOTAL (WAVE_BASE + 4*PW_STRIDE)   // 162880 (<= 163840)

#define MFMA(a,b,c) __builtin_amdgcn_mfma_f32_16x16x32_bf16((a),(b),(c),0,0,0)

__global__ __launch_bounds__(256, 1)
void winattn_kernel(const float* __restrict__ x,
                    const float* __restrict__ mask,
                    const float* __restrict__ qkvK,
                    const float* __restrict__ qkvB,
                    const float* __restrict__ projK,
                    const float* __restrict__ projB,
                    const float* __restrict__ biasT,
                    float* __restrict__ out)
{
    extern __shared__ __align__(16) char smem[];
    const int tid    = threadIdx.x;
    const int lane   = tid & 63;
    const int waveid = tid >> 6;
    const int mi     = lane & 15;   // n-index / m-index inside a 16-tile
    const int g      = lane >> 4;   // k-group (0..3)

    // ---- zero ALL of LDS: no uninitialized read is possible anywhere ----
    for (int i = tid; i < SMEM_TOTAL/4; i += 256)
        ((unsigned int*)smem)[i] = 0u;
    __syncthreads();

    // ---- stage Wqkv [96 k][288 n] fp32 -> bf16 fragment layout ----
    // chunk = (tile t = n/16)*3 + (kt = k/32); within chunk: per-lane 16B at
    // mi*64 + (g ^ ((mi>>1)&3))*16  (XOR swizzle -> conflict-free b128 reads)
    for (int e = tid; e < 96*288; e += 256) {
        int k = e / 288, n = e % 288;
        int t = n >> 4, mr = n & 15;
        int kt = k >> 5, gg = (k >> 3) & 3, jj = k & 7;
        int gs = gg ^ ((mr >> 1) & 3);
        int off = (t*3 + kt)*512 + mr*32 + gs*8 + jj;   // elements
        ((unsigned short*)(smem + WQ_OFF))[off] = (unsigned short)f2bf(qkvK[e]);
    }
    __syncthreads();

    char* wbuf = smem + WAVE_BASE + waveid*PW_STRIDE;
    const char* zp = smem + ZP_OFF;

    // ---- window-invariant register data ----
    // Wp^T fragments: A[m=outfeat=16t+mi][k=kt*32+g*8+jj] = projK[k][m]
    s16x8 wp[6][3];
#pragma unroll
    for (int t = 0; t < 6; ++t)
#pragma unroll
        for (int kt = 0; kt < 3; ++kt) {
            s16x8 v;
#pragma unroll
            for (int jj = 0; jj < 8; ++jj)
                v[jj] = f2bf(projK[(kt*32 + g*8 + jj)*96 + t*16 + mi]);
            wp[t][kt] = v;
        }
    // qkv bias frags for q/k tiles (rows f = 16t+4g+r), fp32
    f32x4 qb[12];
#pragma unroll
    for (int t = 0; t < 12; ++t) {
        f32x4 v;
#pragma unroll
        for (int r = 0; r < 4; ++r) v[r] = qkvB[t*16 + g*4 + r];
        qb[t] = v;
    }
    // v-tile bias (col f = 192+16t+mi, same for all 4 rows)
    float vbias[6];
#pragma unroll
    for (int t = 0; t < 6; ++t) vbias[t] = qkvB[192 + t*16 + mi];
    // proj bias frags (rows f = 16t+4g+r)
    f32x4 pb[6];
#pragma unroll
    for (int t = 0; t < 6; ++t) {
        f32x4 v;
#pragma unroll
        for (int r = 0; r < 4; ++r) v[r] = projB[t*16 + g*4 + r];
        pb[t] = v;
    }
    // relative-position bias, scores^T orientation: lane holds (j=4g+r, i=mi)
    f32x4 rb[8];
#pragma unroll
    for (int h = 0; h < 8; ++h) {
        f32x4 v;
#pragma unroll
        for (int r = 0; r < 4; ++r) {
            int i = mi, j = g*4 + r;
            int idx = ((i & 3) - (j & 3) + 3)*7 + ((i >> 2) - (j >> 2) + 3);
            v[r] = biasT[idx*8 + h] * LOG2E;
        }
        rb[h] = v;
    }
    // phase-1 LDS write offsets (bytes), per lane, window-invariant
    unsigned qkoff[6], voff[6];
#pragma unroll
    for (int t = 0; t < 6; ++t) {
        int f0 = t*16 + g*4;                       // q/k: rows f, tok = mi
        qkoff[t] = (unsigned)(mi*272 + (f0/12)*32 + (f0%12)*2);
        int f3 = t*16 + mi;                        // v: col f, toks = 4g..4g+3
        voff[t]  = (unsigned)((f3/12)*576 + (f3%12)*48 + g*8);
    }
    const unsigned lane_woff = (unsigned)(mi*64 + ((g ^ ((mi >> 1) & 3)) * 16));

    const int wave_global = blockIdx.x*4 + waveid;
    const int w0 = wave_global * WIN_PER_WAVE;

    // ---- prefetch first window's x + mask (raw fp32) ----
    f32x4 xa[3], xb[3], mraw;
    {
        const float* xw = x + w0*1536;
#pragma unroll
        for (int kt = 0; kt < 3; ++kt) {
            xa[kt] = *(const f32x4*)(xw + mi*96 + kt*32 + g*8);
            xb[kt] = *(const f32x4*)(xw + mi*96 + kt*32 + g*8 + 4);
        }
        mraw = *(const f32x4*)(mask + (w0 % LBASE)*256 + mi*16 + g*4);
    }

    for (int it = 0; it < WIN_PER_WAVE; ++it) {
        const int w = w0 + it;

        // convert current window's x to bf16 fragments
        s16x8 xf[3];
#pragma unroll
        for (int kt = 0; kt < 3; ++kt) {
            s16x8 v;
#pragma unroll
            for (int r = 0; r < 4; ++r) { v[r] = f2bf(xa[kt][r]); v[4+r] = f2bf(xb[kt][r]); }
            xf[kt] = v;
        }
        f32x4 mk = mraw;
        mk *= LOG2E;

        // issue next window's global loads now; consumed at next iteration top
        {
            const int wn = (it + 1 < WIN_PER_WAVE) ? (w + 1) : w;   // last iter: dummy in-bounds
            const float* xn = x + wn*1536;
#pragma unroll
            for (int kt = 0; kt < 3; ++kt) {
                xa[kt] = *(const f32x4*)(xn + mi*96 + kt*32 + g*8);
                xb[kt] = *(const f32x4*)(xn + mi*96 + kt*32 + g*8 + 4);
            }
            mraw = *(const f32x4*)(mask + (wn % LBASE)*256 + mi*16 + g*4);
        }

        // ---- phase 1: qkv = x@Wqkv + b ----
        // q,k tiles: D = (Wqkv^T) x^T -> lane (row f=16t+4g+r, col tok=mi)
#pragma unroll
        for (int t = 0; t < 12; ++t) {
            f32x4 c = qb[t];
#pragma unroll
            for (int kt = 0; kt < 3; ++kt) {
                s16x8 wf = *(const s16x8*)(smem + WQ_OFF + (t*3 + kt)*1024 + lane_woff);
                c = MFMA(wf, xf[kt], c);
            }
            const float scl = (t < 6) ? QSCALE : 1.0f;   // fold scale*log2e into q
            s16x4 o;
#pragma unroll
            for (int r = 0; r < 4; ++r) o[r] = f2bf(c[r]*scl);
            char* dst = wbuf + ((t < 6) ? PW_Q : PW_K) + qkoff[(t < 6) ? t : (t-6)];
            *(s16x4*)dst = o;                            // ds_write_b64
        }
        // v tiles: D = x@Wv -> lane (row tok=4g+r, col f) -> v_s[h][d][tok]
#pragma unroll
        for (int t = 0; t < 6; ++t) {
            f32x4 c = { vbias[t], vbias[t], vbias[t], vbias[t] };
#pragma unroll
            for (int kt = 0; kt < 3; ++kt) {
                s16x8 wf = *(const s16x8*)(smem + WQ_OFF + ((12+t)*3 + kt)*1024 + lane_woff);
                c = MFMA(xf[kt], wf, c);
            }
            s16x4 o;
#pragma unroll
            for (int r = 0; r < 4; ++r) o[r] = f2bf(c[r]);
            *(s16x4*)(wbuf + PW_V + voff[t]) = o;
        }
        lds_fence();   // q/k/v visible to phase 2

        // ---- phase 2: ALL 8 HEADS BATCHED (ILP instead of serial chains) ----
        // scores^T = k q^T : A=k-frag, B=q-frag (K = d, zero-padded 12->32)
        f32x4 sc[8];
#pragma unroll
        for (int h = 0; h < 8; ++h) {
            const char* qp = (g < 2) ? (wbuf + PW_Q + mi*272 + h*32 + g*16) : zp;
            const char* kp = (g < 2) ? (wbuf + PW_K + mi*272 + h*32 + g*16) : zp;
            s16x8 kf = *(const s16x8*)kp;
            s16x8 qf = *(const s16x8*)qp;
            f32x4 c = rb[h] + mk;
            sc[h] = MFMA(kf, qf, c);   // lane: (j = 4g+r, i = mi), log2-domain
        }
        // softmax over j for all heads: 8 independent chains, shfl/exp2 pipeline
#pragma unroll
        for (int h = 0; h < 8; ++h) {
            float m = fmaxf(fmaxf(sc[h][0], sc[h][1]), fmaxf(sc[h][2], sc[h][3]));
            m = fmaxf(m, __shfl_xor(m, 16, 64));
            m = fmaxf(m, __shfl_xor(m, 32, 64));
            float p0 = exp2f(sc[h][0]-m), p1 = exp2f(sc[h][1]-m),
                  p2 = exp2f(sc[h][2]-m), p3 = exp2f(sc[h][3]-m);
            float s = (p0+p1) + (p2+p3);
            s += __shfl_xor(s, 16, 64);
            s += __shfl_xor(s, 32, 64);
            float rs = 1.0f / s;
            s16x4 av; av[0]=f2bf(p0*rs); av[1]=f2bf(p1*rs); av[2]=f2bf(p2*rs); av[3]=f2bf(p3*rs);
            *(s16x4*)(wbuf + PW_A + h*1280 + mi*80 + g*8) = av;  // a_s[h][i=mi][j=4g..4g+3]
        }
        lds_fence();   // ONE fence for all 8 heads' attn rows

        // out^T = v^T attn^T : A = v_s[h][d=mi][tok 8], B = a_s[h][i=mi][j 8]
#pragma unroll
        for (int h = 0; h < 8; ++h) {
            s16x8 af = *(const s16x8*)(wbuf + PW_A + h*1280 + mi*80 + g*16);
            const char* vp = (g < 2 && mi < 12) ? (wbuf + PW_V + h*576 + mi*48 + g*16) : zp;
            s16x8 vf = *(const s16x8*)vp;
            f32x4 z = {0.f, 0.f, 0.f, 0.f};
            f32x4 oc = MFMA(vf, af, z);              // lane: (d = 4g+r, i = mi)
            if (g < 3) {                             // d=12..15 invalid
                s16x4 ov; ov[0]=f2bf(oc[0]); ov[1]=f2bf(oc[1]); ov[2]=f2bf(oc[2]); ov[3]=f2bf(oc[3]);
                *(s16x4*)(wbuf + PW_O + mi*208 + h*24 + g*8) = ov;  // o_s[tok=mi][h*12+4g..]
            }
        }
        lds_fence();   // o_s visible to phase 3

        // ---- phase 3: final^T = Wp^T o^T + b ; output fp32 ----
        s16x8 of[3];
#pragma unroll
        for (int kt = 0; kt < 3; ++kt)
            of[kt] = *(const s16x8*)(wbuf + PW_O + mi*208 + kt*64 + g*16);
        float* op = out + w*1536 + mi*96 + g*4;
#pragma unroll
        for (int t = 0; t < 6; ++t) {
            f32x4 c = pb[t];
            c = MFMA(wp[t][0], of[0], c);
            c = MFMA(wp[t][1], of[1], c);
            c = MFMA(wp[t][2], of[2], c);
            *(f32x4*)(op + t*16) = c;                // out[w][tok=mi][16t+4g .. +3] fp32
        }
        // NOTE: no per-window __syncthreads — waves own disjoint LDS regions,
        // WQ is read-only after init, and wave-local DS ordering + the fences
        // above give all required write->read ordering.
    }
}

extern "C" void kernel_launch(void* const* d_in, const int* in_sizes, int n_in,
                              void* d_out, int out_size, void* d_ws, size_t ws_size,
                              hipStream_t stream) {
    const float* x     = (const float*)d_in[0];
    const float* mask  = (const float*)d_in[1];
    const float* qkvK  = (const float*)d_in[2];
    const float* qkvB  = (const float*)d_in[3];
    const float* projK = (const float*)d_in[4];
    const float* projB = (const float*)d_in[5];
    const float* biasT = (const float*)d_in[6];

    (void)in_sizes; (void)n_in; (void)out_size; (void)d_ws; (void)ws_size;

    hipFuncSetAttribute((const void*)winattn_kernel,
                        hipFuncAttributeMaxDynamicSharedMemorySize, SMEM_TOTAL);
    winattn_kernel<<<256, 256, SMEM_TOTAL, stream>>>(
        x, mask, qkvK, qkvB, projK, projB, biasT, (float*)d_out);
}